// Round 1
// 426.043 us; speedup vs baseline: 1.0570x; 1.0570x over previous
//
#include <hip/hip_runtime.h>
#include <math.h>

// Problem constants
#define NPIX   131072      // 32*64*64 pixels
#define KCODES 512
#define DIM    64
#define HW     4096        // 64*64
#define CHW    262144      // 64*4096

// Output layout (floats, concatenated in reference return order)
#define O_Q    1ll
#define O_PERP 8388609ll
#define O_ENC  8388610ll
#define O_IDX  75497474ll

// ws layout (floats): [0] loss accum, [1..512] counts (u32), [513..1024] esq

// Replicate numpy pairwise_sum of x**2 for n=64 (8 accs, stride-8, pairwise combine).
__device__ __forceinline__ float np_sumsq64(const float (&x)[64]) {
#pragma clang fp contract(off)
  float r0 = x[0]*x[0], r1 = x[1]*x[1], r2 = x[2]*x[2], r3 = x[3]*x[3];
  float r4 = x[4]*x[4], r5 = x[5]*x[5], r6 = x[6]*x[6], r7 = x[7]*x[7];
#pragma unroll
  for (int i = 8; i < 64; i += 8) {
    r0 += x[i+0]*x[i+0];
    r1 += x[i+1]*x[i+1];
    r2 += x[i+2]*x[i+2];
    r3 += x[i+3]*x[i+3];
    r4 += x[i+4]*x[i+4];
    r5 += x[i+5]*x[i+5];
    r6 += x[i+6]*x[i+6];
    r7 += x[i+7]*x[i+7];
  }
  return ((r0+r1)+(r2+r3))+((r4+r5)+(r6+r7));
}

// Prep: zero loss accumulator + counts, compute esq[k] (np-pairwise) into ws.
__global__ void vq_prep(const float* __restrict__ emb, float* __restrict__ ws) {
  const int t = threadIdx.x;  // 512 threads
  if (t == 0) ws[0] = 0.0f;
  ((unsigned*)ws)[1 + t] = 0u;
  float x[64];
  const float* e = emb + t * DIM;
#pragma unroll
  for (int d = 0; d < 64; ++d) x[d] = e[d];
  ws[513 + t] = np_sumsq64(x);
}

// Main: round-8 overlap restructure.
// 512 threads = 128 px x 512 codes per block, grid 1024. Per-thread tile is
// unchanged (8px x 8codes, acc=64 regs) so dist math is bit-identical to the
// passing rounds: ascending-d fmaf chain, (zsq+esq)-2*dot, ascending-k scan,
// strict <, butterfly tie-break to lower k == np.argmin exactly.
// New vs round 7:
//  (a) 128-px blocks halve per-pixel staging/barrier/epilogue overhead;
//  (b) next ET slice is prefetched into registers right after the consume
//      barrier -> global latency hides under the 16-dl FMA loop, no exposed
//      load between the two slice barriers;
//  (c) the 256KB/block of encoding ZEROS (known a priori) stream out in 8
//      batches interleaved with the compute slices -> HBM write drain
//      overlaps FMA instead of forming a per-block tail. The single 1.0 per
//      row is a 4B scatter after __syncthreads (hipcc drains vmcnt(0) before
//      s_barrier, so all zero-stores complete first; the line is still dirty
//      in this XCD's L2, so the scatter merges without HBM RMW).
// __launch_bounds__(512,4): min 4 waves/SIMD -> <=128 (V+A)GPRs/wave ->
// 2 blocks/CU = 16 waves/CU (512-thread blocks make occupancy granularity
// coarse: without the bound, 129 VGPRs would mean 1 block/CU = 25%).
__global__ __launch_bounds__(512, 4)
void vq_main(
    const float* __restrict__ z, const float* __restrict__ emb,
    float* __restrict__ out, float* __restrict__ ws)
{
  __shared__ float ET_s[16 * 256];   // 16KB: 16-d slice of embT, one code-half
  __shared__ float z_l[64 * 128];    // 32KB: z_l[d][px]
  __shared__ float esq_l[512];
  __shared__ float zsq_l[128];
  __shared__ int   ridx_l[128];
  __shared__ float wsum[8];

  const int t   = threadIdx.x;       // 0..511
  const int ci  = t & 31;
  const int pi  = t >> 5;            // 0..15
  const int blk = blockIdx.x;        // grid = 1024
  const int n0  = blk * 128;         // 128 consecutive pixels (same batch b)
  const int b   = n0 >> 12;
  const int hw0 = n0 & 4095;
  const float* zg = z + (size_t)b * CHW + hw0;

  esq_l[t] = ws[513 + t];

  // Stage z_l[d][px]: 64 rows of 128 floats (coalesced float4 global reads).
  {
    const int i     = t & 31;        // float4 index within row
    const int dbase = t >> 5;        // 0..15
#pragma unroll
    for (int r = 0; r < 4; ++r) {
      const int d = dbase + 16 * r;
      *(float4*)&z_l[d * 128 + 4 * i] = *(const float4*)(zg + (size_t)d * HW + 4 * i);
    }
  }

  // ET register prefetch for (H=0, s=0); issued before the barrier so it
  // overlaps the z staging wait.
  const int ec = t & 255;            // code within half
  const int eh = t >> 8;             // 0/1: which 8-d subrow of the slice
  float4 p0, p1;
  {
    const float* er = emb + (size_t)ec * 64 + 8 * eh;
    p0 = *(const float4*)(er + 0);
    p1 = *(const float4*)(er + 4);
  }

  __syncthreads();

  // Exact per-pixel zsq (np pairwise pattern), one thread per pixel.
  if (t < 128) {
    float x[64];
#pragma unroll
    for (int d = 0; d < 64; ++d) x[d] = z_l[d * 128 + t];
    zsq_l[t] = np_sumsq64(x);
  }

  float bd[8];
  int   bk[8];
#pragma unroll
  for (int j = 0; j < 8; ++j) { bd[j] = INFINITY; bk[j] = 0; }

  float2* encb = (float2*)(out + O_ENC) + (size_t)n0 * 256;  // 8B-aligned
  const float2 zz = make_float2(0.0f, 0.0f);

  for (int H = 0; H < 2; ++H) {
    float acc[8][8];
#pragma unroll
    for (int j = 0; j < 8; ++j)
#pragma unroll
      for (int c = 0; c < 8; ++c) acc[j][c] = 0.0f;

    for (int s = 0; s < 4; ++s) {
      __syncthreads();  // previous slice consumed (first: z_l/zsq_l published)
      // ET_s[dl][c] <- prefetched regs (8 conflict-free ds_write_b32).
      {
        const float tmp[8] = {p0.x, p0.y, p0.z, p0.w, p1.x, p1.y, p1.z, p1.w};
#pragma unroll
        for (int dl = 0; dl < 8; ++dl) ET_s[(8 * eh + dl) * 256 + ec] = tmp[dl];
      }
      __syncthreads();

      // Prefetch next slice into regs; completes under the dl-loop.
      if (!(H == 1 && s == 3)) {
        const int nH = (s < 3) ? H : 1;
        const int ns = (s < 3) ? (s + 1) : 0;
        const float* er = emb + (size_t)(256 * nH + ec) * 64 + 16 * ns + 8 * eh;
        p0 = *(const float4*)(er + 0);
        p1 = *(const float4*)(er + 4);
      }

      // Stream one batch (32KB/block) of encoding zeros; drain hides under
      // the FMA loop, forced complete by the vmcnt(0) at the next barrier.
      {
        const int batch = 4 * H + s;
#pragma unroll
        for (int u = 0; u < 8; ++u)
          encb[(size_t)batch * 4096 + u * 512 + t] = zz;
      }

#pragma unroll 2
      for (int dl = 0; dl < 16; ++dl) {
        const float* zp = &z_l[(16 * s + dl) * 128 + 8 * pi];
        const float4 za0 = *(const float4*)(zp + 0);
        const float4 za1 = *(const float4*)(zp + 4);
        const float* ep = &ET_s[dl * 256 + 4 * ci];
        const float4 e0 = *(const float4*)(ep + 0);     // codes 256H+4ci+0..3
        const float4 e1 = *(const float4*)(ep + 128);   // codes 256H+128+4ci..
        const float zr[8] = {za0.x, za0.y, za0.z, za0.w,
                             za1.x, za1.y, za1.z, za1.w};
        const float er_[8] = {e0.x, e0.y, e0.z, e0.w,
                              e1.x, e1.y, e1.z, e1.w};
#pragma unroll
        for (int j = 0; j < 8; ++j)
#pragma unroll
          for (int c = 0; c < 8; ++c)
            acc[j][c] = fmaf(zr[j], er_[c], acc[j][c]);
      }
    }

    // dist + running argmin for this half; ascending (q,r) = ascending k.
#pragma unroll
    for (int q = 0; q < 2; ++q)
#pragma unroll
      for (int r = 0; r < 4; ++r) {
        const int k = 256 * H + 128 * q + 4 * ci + r;
        const float eq = esq_l[k];
#pragma unroll
        for (int j = 0; j < 8; ++j) {
          const float dist = (zsq_l[8 * pi + j] + eq) - 2.0f * acc[j][4 * q + r];
          if (dist < bd[j]) { bd[j] = dist; bk[j] = k; }
        }
      }
  }

  // Butterfly merge across the 32 ci-lanes (tie-break: lower k), exact.
  // Lanes 0..31 / 32..63 of each wave hold fixed pi, so masks 16..1 stay
  // within a pi group — identical semantics to the 256-thread rounds.
#pragma unroll
  for (int m = 16; m >= 1; m >>= 1) {
#pragma unroll
    for (int j = 0; j < 8; ++j) {
      const float od = __shfl_xor(bd[j], m, 64);
      const int   ok = __shfl_xor(bk[j], m, 64);
      if (od < bd[j] || (od == bd[j] && ok < bk[j])) { bd[j] = od; bk[j] = ok; }
    }
  }
  if (ci == 0) {
#pragma unroll
    for (int j = 0; j < 8; ++j) ridx_l[8 * pi + j] = bk[j];
  }
  __syncthreads();  // publishes ridx_l AND drains all enc zero-stores

  // ---- epilogue (all 8 waves) ----
  if (t < 128) {
    const int k = ridx_l[t];
    out[O_IDX + n0 + t] = (float)k;
    atomicAdd((unsigned*)ws + 1 + k, 1u);
    // One-hot scatter: zero at this slot is already globally complete.
    out[O_ENC + (size_t)(n0 + t) * 512 + k] = 1.0f;
  }

  // quantized (transposed back to [B,C,H,W]) + loss, distributed: thread
  // (px = t&127, dq = t>>7) handles 16 d's of one pixel; stores coalesced.
  {
    const int px = t & 127;
    const int dq = t >> 7;
    const int k  = ridx_l[px];
    const float* e0 = emb + ((size_t)k << 6);
    float* q0 = out + O_Q + (size_t)b * CHW + hw0 + px;
    float lsum = 0.0f;
#pragma unroll
    for (int j = 0; j < 16; ++j) {
      const int d = dq * 16 + j;
      const float ev = e0[d];
      const float df = ev - z_l[d * 128 + px];
      lsum = fmaf(df, df, lsum);
      q0[(size_t)d * HW] = ev;
    }
#pragma unroll
    for (int off = 32; off > 0; off >>= 1) lsum += __shfl_down(lsum, off, 64);
    if ((t & 63) == 0) wsum[t >> 6] = lsum;
  }
  __syncthreads();
  if (t == 0)
    atomicAdd(ws, ((wsum[0] + wsum[1]) + (wsum[2] + wsum[3])) +
                  ((wsum[4] + wsum[5]) + (wsum[6] + wsum[7])));
}

// Finalize: perplexity from counts (exact: counts/2^17), loss mean.
__global__ void vq_fin(float* __restrict__ out, const float* __restrict__ ws) {
  __shared__ float red[8];
  const int t = threadIdx.x;  // 512
  const unsigned* counts = (const unsigned*)ws + 1;
  const float p = (float)counts[t] * (1.0f / 131072.0f);
  float h = p * logf(p + 1e-10f);
#pragma unroll
  for (int off = 32; off > 0; off >>= 1) h += __shfl_down(h, off, 64);
  if ((t & 63) == 0) red[t >> 6] = h;
  __syncthreads();
  if (t == 0) {
    float H = 0.0f;
#pragma unroll
    for (int w = 0; w < 8; ++w) H += red[w];
    out[O_PERP] = expf(-H);
    out[0] = 1.25f * ws[0] * (1.0f / 8388608.0f);
  }
}

extern "C" void kernel_launch(void* const* d_in, const int* in_sizes, int n_in,
                              void* d_out, int out_size, void* d_ws, size_t ws_size,
                              hipStream_t stream) {
  const float* z   = (const float*)d_in[0];
  const float* emb = (const float*)d_in[1];
  float* out = (float*)d_out;
  float* ws  = (float*)d_ws;

  vq_prep<<<1, 512, 0, stream>>>(emb, ws);
  vq_main<<<1024, 512, 0, stream>>>(z, emb, out, ws);
  vq_fin<<<1, 512, 0, stream>>>(out, ws);
}